// Round 8
// baseline (320.377 us; speedup 1.0000x reference)
//
#include <hip/hip_runtime.h>
#include <math.h>

// Problem constants (fixed by setup_inputs)
#define B_    8
#define T_    8192
#define LIN   1536
#define D_    768
#define H_    8
#define E_    96
#define TT    32            // tokens per block in kB
#define NWA   4096          // total waves in kA (1024 blocks x 4 waves)
#define NCH3  128           // chunks per batch in k3
#define CHT3  (T_ / NCH3)   // 64 tokens per chunk

typedef float f32x4 __attribute__((ext_vector_type(4)));
typedef short s16x8 __attribute__((ext_vector_type(8)));
typedef short s16x2 __attribute__((ext_vector_type(2)));

static __device__ __forceinline__ float fast_sigmoid(float v) {
    return 1.0f / (1.0f + __expf(-v));
}
static __device__ __forceinline__ float fast_tanh(float v) {
    float t = __expf(-2.0f * v);
    return (1.0f - t) / (1.0f + t);
}
static __device__ __forceinline__ short f2bf(float f) {   // RNE f32 -> bf16 bits
    unsigned u = __float_as_uint(f);
    unsigned r = (u + 0x7FFFu + ((u >> 16) & 1u)) >> 16;
    return (short)r;
}

// ---------------------------------------------------------------------------
// Kernel 0: weight prep. Wa,Wb [h][e][f] f32 -> wtA,wtB [h][f][e] bf16.
// ---------------------------------------------------------------------------
__global__ __launch_bounds__(256)
void k0_wprep(const float* __restrict__ Wa, const float* __restrict__ Wb,
              short* __restrict__ wtA, short* __restrict__ wtB)
{
    int o = blockIdx.x * 256 + threadIdx.x;
    if (o >= H_ * E_ * E_) return;
    int e = o % E_;
    int f = (o / E_) % E_;
    int h = o / (E_ * E_);
    int in = h * E_ * E_ + e * E_ + f;
    wtA[o] = f2bf(Wa[in]);
    wtB[o] = f2bf(Wb[in]);
}

// ---------------------------------------------------------------------------
// Kernel A: resize + LayerNorm, one wave per token, grid-stride. No LDS.
// Register-local resize (1535 = 2*767+1 => i0(j)=2j for j<767, both taps in
// the lane's own 4 floats; j=767 clamp fixup). Lane's 12 outputs are stored
// feature-major as 6 contiguous ushort2 -> fully coalesced 256B stores.
// Also stores per-token mu/rs for the linear pooling path.
// ---------------------------------------------------------------------------
__global__ __launch_bounds__(256)
void kA_resln(const float* __restrict__ x,
              const float* __restrict__ gamma, const float* __restrict__ beta,
              short* __restrict__ xnb, float* __restrict__ muv, float* __restrict__ rsv)
{
    const int tid  = threadIdx.x;
    const int lane = tid & 63;
    const int wv   = tid >> 6;
    const int gw   = blockIdx.x * 4 + wv;   // 0..NWA-1

    const float SCALE = (float)(1535.0 / 767.0);
    float gm[12], btv[12], wl[12], um[12];
    #pragma unroll
    for (int c = 0; c < 6; ++c)
        #pragma unroll
        for (int d = 0; d < 2; ++d) {
            int k = 2 * c + d;
            int j = 128 * c + 2 * lane + d;
            float pos = (float)j * SCALE;
            int a = (int)floorf(pos);
            if (a > LIN - 1) a = LIN - 1;
            wl[k] = pos - (float)a;
            um[k] = 1.0f - wl[k];
            gm[k]  = gamma[j];
            btv[k] = beta[j];
        }
    const bool last = (lane == 63);

    for (int t = gw; t < B_ * T_; t += NWA) {
        const float* xrow = x + (size_t)t * LIN;

        f32x4 L[6];
        #pragma unroll
        for (int c = 0; c < 6; ++c)
            L[c] = *(const f32x4*)&xrow[256 * c + 4 * lane];

        float xr[12];
        float sum = 0.0f, ssq = 0.0f;
        #pragma unroll
        for (int c = 0; c < 6; ++c)
            #pragma unroll
            for (int d = 0; d < 2; ++d) {
                int k = 2 * c + d;
                float lo = d ? L[c][2] : L[c][0];
                float hi = d ? L[c][3] : L[c][1];
                if (c == 5 && d == 1 && last) lo = L[5][3];  // j=767 clamp
                float v = lo * um[k] + hi * wl[k];
                xr[k] = v; sum += v; ssq = fmaf(v, v, ssq);
            }
        #pragma unroll
        for (int o = 1; o < 64; o <<= 1) {
            sum += __shfl_xor(sum, o, 64);
            ssq += __shfl_xor(ssq, o, 64);
        }
        float mu = sum * (1.0f / D_);
        float rs = 1.0f / sqrtf(ssq * (1.0f / D_) - mu * mu + 1e-5f);
        if (lane == 0) { muv[t] = mu; rsv[t] = rs; }

        short* dst = xnb + (size_t)t * D_;
        #pragma unroll
        for (int c = 0; c < 6; ++c) {
            s16x2 p;
            p[0] = f2bf((xr[2 * c]     - mu) * rs * gm[2 * c]     + btv[2 * c]);
            p[1] = f2bf((xr[2 * c + 1] - mu) * rs * gm[2 * c + 1] + btv[2 * c + 1]);
            *(s16x2*)&dst[128 * c + 2 * lane] = p;
        }
    }
}

// ---------------------------------------------------------------------------
// Kernel B: MFMA scoring. Stage 1: coalesced s16x8 loads of the 32-token tile
// (feature-major), scatter into head-major XOR-swizzled LDS tile (R4-proven
// layout). One __syncthreads. Stage 2: verbatim R4 phase B.
// ---------------------------------------------------------------------------
__global__ __launch_bounds__(256)
void kB_score(const short* __restrict__ xnb,
              const short* __restrict__ wtA, const short* __restrict__ wtB,
              const float* __restrict__ ba, const float* __restrict__ bb,
              const float* __restrict__ Wc, const float* __restrict__ bc,
              float* __restrict__ s_out)
{
    __shared__ __align__(16) short xnt[TT * D_];   // 48 KB bf16 tile
    __shared__ float red2[TT][2];

    const int tid  = threadIdx.x;
    const int lane = tid & 63;
    const int wv   = tid >> 6;
    const int bt0  = blockIdx.x * TT;

    // ---- Stage 1: global (feature-major) -> LDS (head-major, swizzled) ----
    // 3072 16B chunks; chunk c: tok = c/96, e = c%96, holds j = e*8 + h, h=0..7.
    #pragma unroll
    for (int i = 0; i < 12; ++i) {
        int chunk = i * 256 + tid;
        int tok   = chunk / 96;
        int e     = chunk % 96;
        s16x8 v = *(const s16x8*)&xnb[(size_t)(bt0 + tok) * D_ + e * 8];
        int base = tok * D_;
        int swz  = (tok & 7) << 3;
        #pragma unroll
        for (int h = 0; h < 8; ++h) {
            int sidx = (base + h * E_ + e) ^ swz;
            xnt[sidx] = v[h];
        }
    }
    __syncthreads();

    // ---- Stage 2: MFMA scoring (verbatim R4, verified) ----
    const int mtile = wv & 1;
    const int hg    = wv >> 1;
    const int ln15  = lane & 15;
    const int q     = lane >> 4;
    const int tokA  = mtile * 16 + ln15;
    const int swzA  = (tokA & 7) << 3;

    float hacc[4] = {0.0f, 0.0f, 0.0f, 0.0f};

    #pragma unroll
    for (int hh = 0; hh < 4; ++hh) {
        const int h = hg * 4 + hh;
        s16x8 afr[3];
        #pragma unroll
        for (int kk = 0; kk < 3; ++kk) {
            int sidx = (tokA * D_ + h * E_ + kk * 32 + q * 8) ^ swzA;
            afr[kk] = *(const s16x8*)&xnt[sidx];
        }
        f32x4 accA[6], accG[6];
        #pragma unroll
        for (int nt = 0; nt < 6; ++nt) {
            accA[nt] = (f32x4){0.f, 0.f, 0.f, 0.f};
            accG[nt] = (f32x4){0.f, 0.f, 0.f, 0.f};
        }
        #pragma unroll
        for (int nt = 0; nt < 6; ++nt) {
            const short* rowA = wtA + h * (E_ * E_) + (nt * 16 + ln15) * E_ + q * 8;
            const short* rowB = wtB + h * (E_ * E_) + (nt * 16 + ln15) * E_ + q * 8;
            #pragma unroll
            for (int kk = 0; kk < 3; ++kk) {
                s16x8 bA = *(const s16x8*)(rowA + kk * 32);
                s16x8 bG = *(const s16x8*)(rowB + kk * 32);
                accA[nt] = __builtin_amdgcn_mfma_f32_16x16x32_bf16(afr[kk], bA, accA[nt], 0, 0, 0);
                accG[nt] = __builtin_amdgcn_mfma_f32_16x16x32_bf16(afr[kk], bG, accG[nt], 0, 0, 0);
            }
        }
        float v0 = 0.f, v1 = 0.f, v2 = 0.f, v3 = 0.f;
        #pragma unroll
        for (int nt = 0; nt < 6; ++nt) {
            int f = nt * 16 + ln15;
            float bav = ba[h * E_ + f];
            float bbv = bb[h * E_ + f];
            float wcv = Wc[h * E_ + f];
            v0 += fast_tanh(accA[nt][0] + bav) * fast_sigmoid(accG[nt][0] + bbv) * wcv;
            v1 += fast_tanh(accA[nt][1] + bav) * fast_sigmoid(accG[nt][1] + bbv) * wcv;
            v2 += fast_tanh(accA[nt][2] + bav) * fast_sigmoid(accG[nt][2] + bbv) * wcv;
            v3 += fast_tanh(accA[nt][3] + bav) * fast_sigmoid(accG[nt][3] + bbv) * wcv;
        }
        hacc[0] += v0; hacc[1] += v1; hacc[2] += v2; hacc[3] += v3;
    }

    #pragma unroll
    for (int r = 0; r < 4; ++r) {
        float v = hacc[r];
        v += __shfl_xor(v, 1, 64);
        v += __shfl_xor(v, 2, 64);
        v += __shfl_xor(v, 4, 64);
        v += __shfl_xor(v, 8, 64);
        hacc[r] = v;
    }
    if (ln15 == 0) {
        #pragma unroll
        for (int r = 0; r < 4; ++r)
            red2[mtile * 16 + q * 4 + r][hg] = hacc[r];
    }
    __syncthreads();

    if (tid < TT) {
        float bcsum = 0.0f;
        #pragma unroll
        for (int h2 = 0; h2 < H_; ++h2) bcsum += bc[h2];
        s_out[bt0 + tid] = (red2[tid][0] + red2[tid][1] + bcsum) * (1.0f / H_);
    }
}

// ---------------------------------------------------------------------------
// Kernel 2: softmax over T per batch; overwrite s with normalized weights.
// ---------------------------------------------------------------------------
__global__ __launch_bounds__(256)
void k2_softmax(float* __restrict__ s)
{
    __shared__ float red[8];
    const int b = blockIdx.x, tid = threadIdx.x, lane = tid & 63, wv = tid >> 6;
    float* sb = s + (size_t)b * T_;

    float m = -INFINITY;
    for (int t = tid; t < T_; t += 256) m = fmaxf(m, sb[t]);
    #pragma unroll
    for (int o = 32; o > 0; o >>= 1) m = fmaxf(m, __shfl_down(m, o, 64));
    if (lane == 0) red[wv] = m;
    __syncthreads();
    m = fmaxf(fmaxf(red[0], red[1]), fmaxf(red[2], red[3]));
    __syncthreads();

    float z = 0.0f;
    for (int t = tid; t < T_; t += 256) z += __expf(sb[t] - m);
    #pragma unroll
    for (int o = 32; o > 0; o >>= 1) z += __shfl_down(z, o, 64);
    if (lane == 0) red[wv] = z;
    __syncthreads();
    z = red[0] + red[1] + red[2] + red[3];
    float inv = 1.0f / z;
    for (int t = tid; t < T_; t += 256) sb[t] = __expf(sb[t] - m) * inv;
}

// ---------------------------------------------------------------------------
// Kernel 3: linear pooling, stage 1. feats = gamma*(resize(S) - M) + beta*W
// where S[i] = sum_t c_t * x[t][i] (c_t = w_t*rs_t), M = sum c_t*mu_t,
// W = sum w_t. Fully coalesced, no sync.
// ---------------------------------------------------------------------------
__global__ __launch_bounds__(256)
void k3_pool(const float* __restrict__ x, const float* __restrict__ w,
             const float* __restrict__ rsv, const float* __restrict__ muv,
             float* __restrict__ partial, float* __restrict__ pm)
{
    const int tid = threadIdx.x;
    const int b   = blockIdx.x / NCH3, ch = blockIdx.x % NCH3;
    const int t0  = b * T_ + ch * CHT3;

    float acc[6] = {0.f, 0.f, 0.f, 0.f, 0.f, 0.f};
    float msum = 0.0f, wsum = 0.0f;

    for (int tt = 0; tt < CHT3; ++tt) {
        int t = t0 + tt;
        const float* xrow = x + (size_t)t * LIN;
        float wt = w[t];
        float c  = wt * rsv[t];
        msum = fmaf(c, muv[t], msum);
        wsum += wt;
        #pragma unroll
        for (int k = 0; k < 6; ++k)
            acc[k] = fmaf(c, xrow[tid + k * 256], acc[k]);
    }

    float* p = partial + (size_t)blockIdx.x * LIN;
    #pragma unroll
    for (int k = 0; k < 6; ++k) p[tid + k * 256] = acc[k];
    if (tid == 0) { pm[blockIdx.x * 2] = msum; pm[blockIdx.x * 2 + 1] = wsum; }
}

// ---------------------------------------------------------------------------
// Kernel 4: reduce chunk partials -> S[1536]; resize + affine -> out[b,768].
// ---------------------------------------------------------------------------
__global__ __launch_bounds__(256)
void k4_reduce(const float* __restrict__ partial, const float* __restrict__ pm,
               const float* __restrict__ gamma, const float* __restrict__ beta,
               float* __restrict__ out)
{
    __shared__ float S[LIN];
    const int b = blockIdx.x, tid = threadIdx.x;

    float a[6] = {0.f, 0.f, 0.f, 0.f, 0.f, 0.f};
    for (int ch = 0; ch < NCH3; ++ch) {
        const float* p = partial + ((size_t)b * NCH3 + ch) * LIN;
        #pragma unroll
        for (int k = 0; k < 6; ++k) a[k] += p[tid + k * 256];
    }
    #pragma unroll
    for (int k = 0; k < 6; ++k) S[tid + k * 256] = a[k];

    float M = 0.0f, W = 0.0f;
    for (int ch = 0; ch < NCH3; ++ch) {
        M += pm[(b * NCH3 + ch) * 2];
        W += pm[(b * NCH3 + ch) * 2 + 1];
    }
    __syncthreads();

    const float SCALE = (float)(1535.0 / 767.0);
    #pragma unroll
    for (int k = 0; k < 3; ++k) {
        int j = tid + k * 256;
        float pos = (float)j * SCALE;
        int a0 = (int)floorf(pos);
        if (a0 > LIN - 1) a0 = LIN - 1;
        float wl = pos - (float)a0;
        int a1 = (a0 + 1 < LIN) ? a0 + 1 : LIN - 1;
        float Sp = S[a0] * (1.0f - wl) + S[a1] * wl;
        out[b * D_ + j] = gamma[j] * (Sp - M) + beta[j] * W;
    }
}

// ---------------------------------------------------------------------------
extern "C" void kernel_launch(void* const* d_in, const int* in_sizes, int n_in,
                              void* d_out, int out_size, void* d_ws, size_t ws_size,
                              hipStream_t stream)
{
    const float* x     = (const float*)d_in[0];
    // d_in[1] = lens (unused: uniform == L_IN, reference ignores it)
    const float* gamma = (const float*)d_in[2];
    const float* beta  = (const float*)d_in[3];
    const float* Wa    = (const float*)d_in[4];
    const float* ba    = (const float*)d_in[5];
    const float* Wb    = (const float*)d_in[6];
    const float* bb    = (const float*)d_in[7];
    const float* Wc    = (const float*)d_in[8];
    const float* bc    = (const float*)d_in[9];
    float* out = (float*)d_out;

    float* ws      = (float*)d_ws;
    float* s       = ws;                                   // B*T f32
    float* muv     = s + B_ * T_;                          // B*T f32
    float* rsv     = muv + B_ * T_;                        // B*T f32
    float* partial = rsv + B_ * T_;                        // B*NCH3*1536 f32
    float* pm      = partial + (size_t)B_ * NCH3 * LIN;    // B*NCH3*2 f32
    short* wtA     = (short*)(pm + B_ * NCH3 * 2);         // H*E*E bf16
    short* wtB     = wtA + H_ * E_ * E_;
    short* xnb     = wtB + H_ * E_ * E_;                   // B*T*D bf16 (96 MB)

    hipLaunchKernelGGL(k0_wprep, dim3((H_ * E_ * E_ + 255) / 256), dim3(256), 0, stream,
                       Wa, Wb, wtA, wtB);
    hipLaunchKernelGGL(kA_resln, dim3(NWA / 4), dim3(256), 0, stream,
                       x, gamma, beta, xnb, muv, rsv);
    hipLaunchKernelGGL(kB_score, dim3(B_ * T_ / TT), dim3(256), 0, stream,
                       xnb, wtA, wtB, ba, bb, Wc, bc, s);
    hipLaunchKernelGGL(k2_softmax, dim3(B_), dim3(256), 0, stream, s);
    hipLaunchKernelGGL(k3_pool, dim3(B_ * NCH3), dim3(256), 0, stream,
                       x, s, rsv, muv, partial, pm);
    hipLaunchKernelGGL(k4_reduce, dim3(B_), dim3(256), 0, stream,
                       partial, pm, gamma, beta, out);
}

// Round 9
// 302.785 us; speedup vs baseline: 1.0581x; 1.0581x over previous
//
#include <hip/hip_runtime.h>
#include <math.h>

// Problem constants (fixed by setup_inputs)
#define B_    8
#define T_    8192
#define LIN   1536
#define D_    768
#define H_    8
#define E_    96
#define TT    32            // tokens per block in kB
#define NWA   8192          // total waves in kA (2048 blocks x 4 waves)
#define NCH3  128           // chunks per batch in k3
#define CHT3  (T_ / NCH3)   // 64 tokens per chunk (16 per wave)

typedef float f32x4 __attribute__((ext_vector_type(4)));
typedef short s16x8 __attribute__((ext_vector_type(8)));
typedef short s16x4 __attribute__((ext_vector_type(4)));

static __device__ __forceinline__ float fast_sigmoid(float v) {
    return 1.0f / (1.0f + __expf(-v));
}
static __device__ __forceinline__ float fast_tanh(float v) {
    float t = __expf(-2.0f * v);
    return (1.0f - t) / (1.0f + t);
}
static __device__ __forceinline__ short f2bf(float f) {   // RNE f32 -> bf16 bits
    unsigned u = __float_as_uint(f);
    unsigned r = (u + 0x7FFFu + ((u >> 16) & 1u)) >> 16;
    return (short)r;
}
static __device__ __forceinline__ float bf2f(short s) {
    return __uint_as_float(((unsigned)(unsigned short)s) << 16);
}

// ---------------------------------------------------------------------------
// Kernel 0: weight prep. Wa,Wb [h][e][f] f32 -> wtA,wtB [h][f][e] bf16.
// ---------------------------------------------------------------------------
__global__ __launch_bounds__(256)
void k0_wprep(const float* __restrict__ Wa, const float* __restrict__ Wb,
              short* __restrict__ wtA, short* __restrict__ wtB)
{
    int o = blockIdx.x * 256 + threadIdx.x;
    if (o >= H_ * E_ * E_) return;
    int e = o % E_;
    int f = (o / E_) % E_;
    int h = o / (E_ * E_);
    int in = h * E_ * E_ + e * E_ + f;
    wtA[o] = f2bf(Wa[in]);
    wtB[o] = f2bf(Wb[in]);
}

// ---------------------------------------------------------------------------
// Kernel A: resize + LayerNorm, one wave per token, grid-stride. No LDS.
// Lane owns output features j = 256c + 4*lane + d (c=0..2, d=0..3).
// i0(j) = 2j exactly (1535 = 2*767+1), so both taps sit in the lane's own
// 8-float chunk x[512c + 8*lane .. +8) = two f32x4 loads (16B/lane each).
// wl uses the exact reference f32 expression. j=767: pos=1535 -> wl=1.0,
// hi tap must be x[1535] (clamp) = L[5][3]. Stores: 3x s16x4 (8B/lane).
// ---------------------------------------------------------------------------
__global__ __launch_bounds__(256)
void kA_resln(const float* __restrict__ x,
              const float* __restrict__ gamma, const float* __restrict__ beta,
              short* __restrict__ xnb)
{
    const int tid  = threadIdx.x;
    const int lane = tid & 63;
    const int wv   = tid >> 6;
    const int gw   = blockIdx.x * 4 + wv;   // 0..NWA-1

    const float SCALE = (float)(1535.0 / 767.0);
    float gm[12], btv[12], wl[12];
    #pragma unroll
    for (int c = 0; c < 3; ++c)
        #pragma unroll
        for (int d = 0; d < 4; ++d) {
            int k = 4 * c + d;
            int j = 256 * c + 4 * lane + d;
            float pos = (float)j * SCALE;
            int a = (int)floorf(pos);
            if (a > LIN - 1) a = LIN - 1;
            wl[k] = pos - (float)a;          // j=767: a=1535, wl=0? pos=1535.0 -> wl=0
            gm[k]  = gamma[j];
            btv[k] = beta[j];
        }
    // Note: for j=767, pos = 767*SCALE. SCALE f32 ~= 2.00130391; product may
    // round to exactly 1535.0 (wl=0, a=1535 -> lo=hi=x[1535]) or slightly
    // below (a=1534 -> taps x[1534],x[1535] like every other j). Either way
    // the expression above matches the reference bit-for-bit, and both taps
    // for j=767 are L[5][2], L[5][3] with the clamp only when a==1535.
    const bool last = (lane == 63);

    for (int t = gw; t < B_ * T_; t += NWA) {
        const float* xrow = x + (size_t)t * LIN;

        f32x4 L[6];
        #pragma unroll
        for (int c = 0; c < 3; ++c) {
            L[2 * c]     = *(const f32x4*)&xrow[512 * c + 8 * lane];
            L[2 * c + 1] = *(const f32x4*)&xrow[512 * c + 8 * lane + 4];
        }

        float xr[12];
        float sum = 0.0f, ssq = 0.0f;
        #pragma unroll
        for (int c = 0; c < 3; ++c)
            #pragma unroll
            for (int d = 0; d < 4; ++d) {
                int k = 4 * c + d;
                float lo = (d < 2) ? ((d & 1) ? L[2 * c][2] : L[2 * c][0])
                                   : ((d & 1) ? L[2 * c + 1][2] : L[2 * c + 1][0]);
                float hi = (d < 2) ? ((d & 1) ? L[2 * c][3] : L[2 * c][1])
                                   : ((d & 1) ? L[2 * c + 1][3] : L[2 * c + 1][1]);
                if (c == 2 && d == 3 && last) {
                    // j = 767: i0 = floor(767*SCALE) could be 1534 or 1535.
                    // If 1535 (wl==0): lo must be x[1535] = L[5][3].
                    if (wl[k] == 0.0f) lo = L[5][3];
                }
                float v = lo * (1.0f - wl[k]) + hi * wl[k];
                xr[k] = v; sum += v; ssq = fmaf(v, v, ssq);
            }
        #pragma unroll
        for (int o = 1; o < 64; o <<= 1) {
            sum += __shfl_xor(sum, o, 64);
            ssq += __shfl_xor(ssq, o, 64);
        }
        float mu = sum * (1.0f / D_);
        float rs = 1.0f / sqrtf(ssq * (1.0f / D_) - mu * mu + 1e-5f);

        short* dst = xnb + (size_t)t * D_;
        #pragma unroll
        for (int c = 0; c < 3; ++c) {
            s16x4 p;
            #pragma unroll
            for (int d = 0; d < 4; ++d) {
                int k = 4 * c + d;
                p[d] = f2bf((xr[k] - mu) * rs * gm[k] + btv[k]);
            }
            *(s16x4*)&dst[256 * c + 4 * lane] = p;
        }
    }
}

// ---------------------------------------------------------------------------
// Kernel B: MFMA scoring. Stage 1: coalesced s16x8 loads of the 32-token tile
// (feature-major), scatter into head-major XOR-swizzled LDS tile (R4-proven
// layout). One __syncthreads. Stage 2: verbatim R4 phase B.  [passed R8]
// ---------------------------------------------------------------------------
__global__ __launch_bounds__(256)
void kB_score(const short* __restrict__ xnb,
              const short* __restrict__ wtA, const short* __restrict__ wtB,
              const float* __restrict__ ba, const float* __restrict__ bb,
              const float* __restrict__ Wc, const float* __restrict__ bc,
              float* __restrict__ s_out)
{
    __shared__ __align__(16) short xnt[TT * D_];   // 48 KB bf16 tile
    __shared__ float red2[TT][2];

    const int tid  = threadIdx.x;
    const int lane = tid & 63;
    const int wv   = tid >> 6;
    const int bt0  = blockIdx.x * TT;

    // ---- Stage 1: global (feature-major) -> LDS (head-major, swizzled) ----
    #pragma unroll
    for (int i = 0; i < 12; ++i) {
        int chunk = i * 256 + tid;
        int tok   = chunk / 96;
        int e     = chunk % 96;
        s16x8 v = *(const s16x8*)&xnb[(size_t)(bt0 + tok) * D_ + e * 8];
        int base = tok * D_;
        int swz  = (tok & 7) << 3;
        #pragma unroll
        for (int h = 0; h < 8; ++h) {
            int sidx = (base + h * E_ + e) ^ swz;
            xnt[sidx] = v[h];
        }
    }
    __syncthreads();

    // ---- Stage 2: MFMA scoring (verbatim R4, verified) ----
    const int mtile = wv & 1;
    const int hg    = wv >> 1;
    const int ln15  = lane & 15;
    const int q     = lane >> 4;
    const int tokA  = mtile * 16 + ln15;
    const int swzA  = (tokA & 7) << 3;

    float hacc[4] = {0.0f, 0.0f, 0.0f, 0.0f};

    #pragma unroll
    for (int hh = 0; hh < 4; ++hh) {
        const int h = hg * 4 + hh;
        s16x8 afr[3];
        #pragma unroll
        for (int kk = 0; kk < 3; ++kk) {
            int sidx = (tokA * D_ + h * E_ + kk * 32 + q * 8) ^ swzA;
            afr[kk] = *(const s16x8*)&xnt[sidx];
        }
        f32x4 accA[6], accG[6];
        #pragma unroll
        for (int nt = 0; nt < 6; ++nt) {
            accA[nt] = (f32x4){0.f, 0.f, 0.f, 0.f};
            accG[nt] = (f32x4){0.f, 0.f, 0.f, 0.f};
        }
        #pragma unroll
        for (int nt = 0; nt < 6; ++nt) {
            const short* rowA = wtA + h * (E_ * E_) + (nt * 16 + ln15) * E_ + q * 8;
            const short* rowB = wtB + h * (E_ * E_) + (nt * 16 + ln15) * E_ + q * 8;
            #pragma unroll
            for (int kk = 0; kk < 3; ++kk) {
                s16x8 bA = *(const s16x8*)(rowA + kk * 32);
                s16x8 bG = *(const s16x8*)(rowB + kk * 32);
                accA[nt] = __builtin_amdgcn_mfma_f32_16x16x32_bf16(afr[kk], bA, accA[nt], 0, 0, 0);
                accG[nt] = __builtin_amdgcn_mfma_f32_16x16x32_bf16(afr[kk], bG, accG[nt], 0, 0, 0);
            }
        }
        float v0 = 0.f, v1 = 0.f, v2 = 0.f, v3 = 0.f;
        #pragma unroll
        for (int nt = 0; nt < 6; ++nt) {
            int f = nt * 16 + ln15;
            float bav = ba[h * E_ + f];
            float bbv = bb[h * E_ + f];
            float wcv = Wc[h * E_ + f];
            v0 += fast_tanh(accA[nt][0] + bav) * fast_sigmoid(accG[nt][0] + bbv) * wcv;
            v1 += fast_tanh(accA[nt][1] + bav) * fast_sigmoid(accG[nt][1] + bbv) * wcv;
            v2 += fast_tanh(accA[nt][2] + bav) * fast_sigmoid(accG[nt][2] + bbv) * wcv;
            v3 += fast_tanh(accA[nt][3] + bav) * fast_sigmoid(accG[nt][3] + bbv) * wcv;
        }
        hacc[0] += v0; hacc[1] += v1; hacc[2] += v2; hacc[3] += v3;
    }

    #pragma unroll
    for (int r = 0; r < 4; ++r) {
        float v = hacc[r];
        v += __shfl_xor(v, 1, 64);
        v += __shfl_xor(v, 2, 64);
        v += __shfl_xor(v, 4, 64);
        v += __shfl_xor(v, 8, 64);
        hacc[r] = v;
    }
    if (ln15 == 0) {
        #pragma unroll
        for (int r = 0; r < 4; ++r)
            red2[mtile * 16 + q * 4 + r][hg] = hacc[r];
    }
    __syncthreads();

    if (tid < TT) {
        float bcsum = 0.0f;
        #pragma unroll
        for (int h2 = 0; h2 < H_; ++h2) bcsum += bc[h2];
        s_out[bt0 + tid] = (red2[tid][0] + red2[tid][1] + bcsum) * (1.0f / H_);
    }
}

// ---------------------------------------------------------------------------
// Kernel 2: softmax over T per batch; overwrite s with normalized weights.
// ---------------------------------------------------------------------------
__global__ __launch_bounds__(256)
void k2_softmax(float* __restrict__ s)
{
    __shared__ float red[8];
    const int b = blockIdx.x, tid = threadIdx.x, lane = tid & 63, wv = tid >> 6;
    float* sb = s + (size_t)b * T_;

    float m = -INFINITY;
    for (int t = tid; t < T_; t += 256) m = fmaxf(m, sb[t]);
    #pragma unroll
    for (int o = 32; o > 0; o >>= 1) m = fmaxf(m, __shfl_down(m, o, 64));
    if (lane == 0) red[wv] = m;
    __syncthreads();
    m = fmaxf(fmaxf(red[0], red[1]), fmaxf(red[2], red[3]));
    __syncthreads();

    float z = 0.0f;
    for (int t = tid; t < T_; t += 256) z += __expf(sb[t] - m);
    #pragma unroll
    for (int o = 32; o > 0; o >>= 1) z += __shfl_down(z, o, 64);
    if (lane == 0) red[wv] = z;
    __syncthreads();
    z = red[0] + red[1] + red[2] + red[3];
    float inv = 1.0f / z;
    for (int t = tid; t < T_; t += 256) sb[t] = __expf(sb[t] - m) * inv;
}

// ---------------------------------------------------------------------------
// Kernel 3: pooling from bf16 xn (96 MB, not 402 MB x re-read).
// feats = sum_t w_t * xn[t]. Wave owns 16 tokens; lane owns 12 features:
// cols 8l..8l+7 (s16x8 load, 16B/lane) + 512+4l..+3 (s16x4, 8B/lane).
// Wave-private accumulators, no sync; partial row per wave.
// ---------------------------------------------------------------------------
__global__ __launch_bounds__(256)
void k3_pool(const short* __restrict__ xnb, const float* __restrict__ w,
             float* __restrict__ partial)
{
    const int tid  = threadIdx.x;
    const int lane = tid & 63;
    const int wv   = tid >> 6;
    const int b    = blockIdx.x / NCH3, ch = blockIdx.x % NCH3;
    const int t0   = b * T_ + ch * CHT3 + wv * 16;

    float acc[12];
    #pragma unroll
    for (int k = 0; k < 12; ++k) acc[k] = 0.0f;

    for (int tt = 0; tt < 16; ++tt) {
        int t = t0 + tt;
        const short* row = xnb + (size_t)t * D_;
        float wt = w[t];
        s16x8 v0 = *(const s16x8*)&row[8 * lane];
        s16x4 v1 = *(const s16x4*)&row[512 + 4 * lane];
        #pragma unroll
        for (int k = 0; k < 8; ++k) acc[k] = fmaf(wt, bf2f(v0[k]), acc[k]);
        #pragma unroll
        for (int k = 0; k < 4; ++k) acc[8 + k] = fmaf(wt, bf2f(v1[k]), acc[8 + k]);
    }

    float* p = partial + ((size_t)blockIdx.x * 4 + wv) * D_;
    *(f32x4*)&p[8 * lane]     = (f32x4){acc[0], acc[1], acc[2], acc[3]};
    *(f32x4*)&p[8 * lane + 4] = (f32x4){acc[4], acc[5], acc[6], acc[7]};
    *(f32x4*)&p[512 + 4 * lane] = (f32x4){acc[8], acc[9], acc[10], acc[11]};
}

// ---------------------------------------------------------------------------
// Kernel 4: reduce 512 wave-partials per batch -> out[b, 768].
// ---------------------------------------------------------------------------
__global__ __launch_bounds__(256)
void k4_reduce(const float* __restrict__ partial, float* __restrict__ out)
{
    const int b = blockIdx.x, tid = threadIdx.x;
    const int NR = NCH3 * 4;
    #pragma unroll
    for (int k = 0; k < 3; ++k) {
        int j = tid + k * 256;
        const float* p = partial + (size_t)b * NR * D_ + j;
        float s = 0.0f;
        for (int c = 0; c < NR; ++c) s += p[(size_t)c * D_];
        out[b * D_ + j] = s;
    }
}

// ---------------------------------------------------------------------------
extern "C" void kernel_launch(void* const* d_in, const int* in_sizes, int n_in,
                              void* d_out, int out_size, void* d_ws, size_t ws_size,
                              hipStream_t stream)
{
    const float* x     = (const float*)d_in[0];
    // d_in[1] = lens (unused: uniform == L_IN, reference ignores it)
    const float* gamma = (const float*)d_in[2];
    const float* beta  = (const float*)d_in[3];
    const float* Wa    = (const float*)d_in[4];
    const float* ba    = (const float*)d_in[5];
    const float* Wb    = (const float*)d_in[6];
    const float* bb    = (const float*)d_in[7];
    const float* Wc    = (const float*)d_in[8];
    const float* bc    = (const float*)d_in[9];
    float* out = (float*)d_out;

    float* ws      = (float*)d_ws;
    float* s       = ws;                                   // B*T f32
    float* partial = s + B_ * T_;                          // B*NCH3*4*768 f32 (12.6 MB)
    short* wtA     = (short*)(partial + (size_t)B_ * NCH3 * 4 * D_);
    short* wtB     = wtA + H_ * E_ * E_;
    short* xnb     = wtB + H_ * E_ * E_;                   // B*T*768 bf16 (96 MB)

    hipLaunchKernelGGL(k0_wprep, dim3((H_ * E_ * E_ + 255) / 256), dim3(256), 0, stream,
                       Wa, Wb, wtA, wtB);
    hipLaunchKernelGGL(kA_resln, dim3(NWA / 4), dim3(256), 0, stream,
                       x, gamma, beta, xnb);
    hipLaunchKernelGGL(kB_score, dim3(B_ * T_ / TT), dim3(256), 0, stream,
                       xnb, wtA, wtB, ba, bb, Wc, bc, s);
    hipLaunchKernelGGL(k2_softmax, dim3(B_), dim3(256), 0, stream, s);
    hipLaunchKernelGGL(k3_pool, dim3(B_ * NCH3), dim3(256), 0, stream,
                       xnb, s, partial);
    hipLaunchKernelGGL(k4_reduce, dim3(B_), dim3(256), 0, stream, partial, out);
}

// Round 10
// 295.990 us; speedup vs baseline: 1.0824x; 1.0230x over previous
//
#include <hip/hip_runtime.h>
#include <math.h>

// Problem constants (fixed by setup_inputs)
#define B_    8
#define T_    8192
#define LIN   1536
#define D_    768
#define H_    8
#define E_    96
#define TT    16            // tokens per block in kB (24KB LDS -> 6 blocks/CU)
#define NWA   8192          // total waves in kA (2048 blocks x 4 waves)
#define NCH3  128           // chunks per batch in k3
#define CHT3  (T_ / NCH3)   // 64 tokens per chunk (16 per wave)

typedef float f32x4 __attribute__((ext_vector_type(4)));
typedef short s16x8 __attribute__((ext_vector_type(8)));
typedef short s16x4 __attribute__((ext_vector_type(4)));

static __device__ __forceinline__ float fast_sigmoid(float v) {
    return 1.0f / (1.0f + __expf(-v));
}
static __device__ __forceinline__ float fast_tanh(float v) {
    float t = __expf(-2.0f * v);
    return (1.0f - t) / (1.0f + t);
}
static __device__ __forceinline__ short f2bf(float f) {   // RNE f32 -> bf16 bits
    unsigned u = __float_as_uint(f);
    unsigned r = (u + 0x7FFFu + ((u >> 16) & 1u)) >> 16;
    return (short)r;
}
static __device__ __forceinline__ float bf2f(short s) {
    return __uint_as_float(((unsigned)(unsigned short)s) << 16);
}

// ---------------------------------------------------------------------------
// Kernel 0: weight prep. Wa,Wb [h][e][f] f32 -> wtA,wtB [h][f][e] bf16.
// ---------------------------------------------------------------------------
__global__ __launch_bounds__(256)
void k0_wprep(const float* __restrict__ Wa, const float* __restrict__ Wb,
              short* __restrict__ wtA, short* __restrict__ wtB)
{
    int o = blockIdx.x * 256 + threadIdx.x;
    if (o >= H_ * E_ * E_) return;
    int e = o % E_;
    int f = (o / E_) % E_;
    int h = o / (E_ * E_);
    int in = h * E_ * E_ + e * E_ + f;
    wtA[o] = f2bf(Wa[in]);
    wtB[o] = f2bf(Wb[in]);
}

// ---------------------------------------------------------------------------
// Kernel A: resize + LayerNorm, one wave per TOKEN-PAIR per iteration.
// Two independent tokens in flight -> two interleaved shuffle-reduce chains
// (halves exposed cross-lane latency), 12 dwordx4 loads issued together.
// Lane owns features j = 256c + 4*lane + d; i0(j)=2j exactly; j=767 fixup.
// Stores: 3x s16x4 (8B/lane), fully coalesced. Math identical to R9 (passed).
// ---------------------------------------------------------------------------
__global__ __launch_bounds__(256)
void kA_resln(const float* __restrict__ x,
              const float* __restrict__ gamma, const float* __restrict__ beta,
              short* __restrict__ xnb)
{
    const int tid  = threadIdx.x;
    const int lane = tid & 63;
    const int wv   = tid >> 6;
    const int gw   = blockIdx.x * 4 + wv;   // 0..NWA-1

    const float SCALE = (float)(1535.0 / 767.0);
    float gm[12], btv[12], wl[12];
    #pragma unroll
    for (int c = 0; c < 3; ++c)
        #pragma unroll
        for (int d = 0; d < 4; ++d) {
            int k = 4 * c + d;
            int j = 256 * c + 4 * lane + d;
            float pos = (float)j * SCALE;
            int a = (int)floorf(pos);
            if (a > LIN - 1) a = LIN - 1;
            wl[k] = pos - (float)a;
            gm[k]  = gamma[j];
            btv[k] = beta[j];
        }
    const bool last = (lane == 63);

    for (int p = gw; p < B_ * T_ / 2; p += NWA) {
        const float* xrow0 = x + (size_t)(2 * p) * LIN;
        const float* xrow1 = xrow0 + LIN;

        f32x4 L0[6], L1[6];
        #pragma unroll
        for (int c = 0; c < 3; ++c) {
            L0[2 * c]     = *(const f32x4*)&xrow0[512 * c + 8 * lane];
            L0[2 * c + 1] = *(const f32x4*)&xrow0[512 * c + 8 * lane + 4];
            L1[2 * c]     = *(const f32x4*)&xrow1[512 * c + 8 * lane];
            L1[2 * c + 1] = *(const f32x4*)&xrow1[512 * c + 8 * lane + 4];
        }

        float xr0[12], xr1[12];
        float sum0 = 0.f, ssq0 = 0.f, sum1 = 0.f, ssq1 = 0.f;
        #pragma unroll
        for (int c = 0; c < 3; ++c)
            #pragma unroll
            for (int d = 0; d < 4; ++d) {
                int k = 4 * c + d;
                int half = (d >> 1);           // 0: L[2c], 1: L[2c+1]
                int idx  = (d & 1) * 2;        // 0 or 2
                float lo0 = half ? L0[2 * c + 1][idx]     : L0[2 * c][idx];
                float hi0 = half ? L0[2 * c + 1][idx + 1] : L0[2 * c][idx + 1];
                float lo1 = half ? L1[2 * c + 1][idx]     : L1[2 * c][idx];
                float hi1 = half ? L1[2 * c + 1][idx + 1] : L1[2 * c][idx + 1];
                if (c == 2 && d == 3 && last && wl[k] == 0.0f) {
                    lo0 = L0[5][3];           // j=767 clamp (pos rounds to 1535.0)
                    lo1 = L1[5][3];
                }
                float v0 = lo0 * (1.0f - wl[k]) + hi0 * wl[k];
                float v1 = lo1 * (1.0f - wl[k]) + hi1 * wl[k];
                xr0[k] = v0; sum0 += v0; ssq0 = fmaf(v0, v0, ssq0);
                xr1[k] = v1; sum1 += v1; ssq1 = fmaf(v1, v1, ssq1);
            }

        #pragma unroll
        for (int o = 1; o < 64; o <<= 1) {
            sum0 += __shfl_xor(sum0, o, 64);
            ssq0 += __shfl_xor(ssq0, o, 64);
            sum1 += __shfl_xor(sum1, o, 64);
            ssq1 += __shfl_xor(ssq1, o, 64);
        }
        float mu0 = sum0 * (1.0f / D_);
        float rs0 = 1.0f / sqrtf(ssq0 * (1.0f / D_) - mu0 * mu0 + 1e-5f);
        float mu1 = sum1 * (1.0f / D_);
        float rs1 = 1.0f / sqrtf(ssq1 * (1.0f / D_) - mu1 * mu1 + 1e-5f);

        short* dst0 = xnb + (size_t)(2 * p) * D_;
        short* dst1 = dst0 + D_;
        #pragma unroll
        for (int c = 0; c < 3; ++c) {
            s16x4 p0, p1;
            #pragma unroll
            for (int d = 0; d < 4; ++d) {
                int k = 4 * c + d;
                p0[d] = f2bf((xr0[k] - mu0) * rs0 * gm[k] + btv[k]);
                p1[d] = f2bf((xr1[k] - mu1) * rs1 * gm[k] + btv[k]);
            }
            *(s16x4*)&dst0[256 * c + 4 * lane] = p0;
            *(s16x4*)&dst1[256 * c + 4 * lane] = p1;
        }
    }
}

// ---------------------------------------------------------------------------
// Kernel B: MFMA scoring, 16-token tile (24KB LDS -> 6 blocks/CU).
// Stage 1: coalesced s16x8 loads (feature-major) -> head-major XOR-swizzled
// LDS (R4-proven layout). Stage 2: wave owns 2 heads x 16 tokens, 72 MFMAs.
// ---------------------------------------------------------------------------
__global__ __launch_bounds__(256)
void kB_score(const short* __restrict__ xnb,
              const short* __restrict__ wtA, const short* __restrict__ wtB,
              const float* __restrict__ ba, const float* __restrict__ bb,
              const float* __restrict__ Wc, const float* __restrict__ bc,
              float* __restrict__ s_out)
{
    __shared__ __align__(16) short xnt[TT * D_];   // 24 KB bf16 tile
    __shared__ float red2[TT][4];

    const int tid  = threadIdx.x;
    const int lane = tid & 63;
    const int wv   = tid >> 6;
    const int bt0  = blockIdx.x * TT;

    // ---- Stage 1: global (feature-major) -> LDS (head-major, swizzled) ----
    // 1536 16B chunks; chunk: tok = c/96, e = c%96; holds j = e*8+h, h=0..7.
    #pragma unroll
    for (int i = 0; i < 6; ++i) {
        int chunk = i * 256 + tid;
        int tok   = chunk / 96;
        int e     = chunk % 96;
        s16x8 v = *(const s16x8*)&xnb[(size_t)(bt0 + tok) * D_ + e * 8];
        int base = tok * D_;
        int swz  = (tok & 7) << 3;
        #pragma unroll
        for (int h = 0; h < 8; ++h) {
            int sidx = (base + h * E_ + e) ^ swz;
            xnt[sidx] = v[h];
        }
    }
    __syncthreads();

    // ---- Stage 2: MFMA scoring; wave = heads {2wv, 2wv+1} x 16 tokens ----
    const int ln15 = lane & 15;
    const int q    = lane >> 4;
    const int tokA = ln15;
    const int swzA = (tokA & 7) << 3;

    float hacc[4] = {0.0f, 0.0f, 0.0f, 0.0f};

    #pragma unroll
    for (int hh = 0; hh < 2; ++hh) {
        const int h = wv * 2 + hh;
        s16x8 afr[3];
        #pragma unroll
        for (int kk = 0; kk < 3; ++kk) {
            int sidx = (tokA * D_ + h * E_ + kk * 32 + q * 8) ^ swzA;
            afr[kk] = *(const s16x8*)&xnt[sidx];
        }
        f32x4 accA[6], accG[6];
        #pragma unroll
        for (int nt = 0; nt < 6; ++nt) {
            accA[nt] = (f32x4){0.f, 0.f, 0.f, 0.f};
            accG[nt] = (f32x4){0.f, 0.f, 0.f, 0.f};
        }
        #pragma unroll
        for (int nt = 0; nt < 6; ++nt) {
            const short* rowA = wtA + h * (E_ * E_) + (nt * 16 + ln15) * E_ + q * 8;
            const short* rowB = wtB + h * (E_ * E_) + (nt * 16 + ln15) * E_ + q * 8;
            #pragma unroll
            for (int kk = 0; kk < 3; ++kk) {
                s16x8 bA = *(const s16x8*)(rowA + kk * 32);
                s16x8 bG = *(const s16x8*)(rowB + kk * 32);
                accA[nt] = __builtin_amdgcn_mfma_f32_16x16x32_bf16(afr[kk], bA, accA[nt], 0, 0, 0);
                accG[nt] = __builtin_amdgcn_mfma_f32_16x16x32_bf16(afr[kk], bG, accG[nt], 0, 0, 0);
            }
        }
        float v0 = 0.f, v1 = 0.f, v2 = 0.f, v3 = 0.f;
        #pragma unroll
        for (int nt = 0; nt < 6; ++nt) {
            int f = nt * 16 + ln15;
            float bav = ba[h * E_ + f];
            float bbv = bb[h * E_ + f];
            float wcv = Wc[h * E_ + f];
            v0 += fast_tanh(accA[nt][0] + bav) * fast_sigmoid(accG[nt][0] + bbv) * wcv;
            v1 += fast_tanh(accA[nt][1] + bav) * fast_sigmoid(accG[nt][1] + bbv) * wcv;
            v2 += fast_tanh(accA[nt][2] + bav) * fast_sigmoid(accG[nt][2] + bbv) * wcv;
            v3 += fast_tanh(accA[nt][3] + bav) * fast_sigmoid(accG[nt][3] + bbv) * wcv;
        }
        hacc[0] += v0; hacc[1] += v1; hacc[2] += v2; hacc[3] += v3;
    }

    #pragma unroll
    for (int r = 0; r < 4; ++r) {
        float v = hacc[r];
        v += __shfl_xor(v, 1, 64);
        v += __shfl_xor(v, 2, 64);
        v += __shfl_xor(v, 4, 64);
        v += __shfl_xor(v, 8, 64);
        hacc[r] = v;
    }
    if (ln15 == 0) {
        #pragma unroll
        for (int r = 0; r < 4; ++r)
            red2[q * 4 + r][wv] = hacc[r];
    }
    __syncthreads();

    if (tid < TT) {
        float bcsum = 0.0f;
        #pragma unroll
        for (int h2 = 0; h2 < H_; ++h2) bcsum += bc[h2];
        s_out[bt0 + tid] = (red2[tid][0] + red2[tid][1] + red2[tid][2] + red2[tid][3]
                            + bcsum) * (1.0f / H_);
    }
}

// ---------------------------------------------------------------------------
// Kernel 2: per-batch softmax constants only: m and 1/z (2 passes, no write-back).
// ---------------------------------------------------------------------------
__global__ __launch_bounds__(256)
void k2_mz(const float* __restrict__ s, float* __restrict__ mz)
{
    __shared__ float red[8];
    const int b = blockIdx.x, tid = threadIdx.x, lane = tid & 63, wv = tid >> 6;
    const float* sb = s + (size_t)b * T_;

    float m = -INFINITY;
    for (int t = tid; t < T_; t += 256) m = fmaxf(m, sb[t]);
    #pragma unroll
    for (int o = 32; o > 0; o >>= 1) m = fmaxf(m, __shfl_down(m, o, 64));
    if (lane == 0) red[wv] = m;
    __syncthreads();
    m = fmaxf(fmaxf(red[0], red[1]), fmaxf(red[2], red[3]));
    __syncthreads();

    float z = 0.0f;
    for (int t = tid; t < T_; t += 256) z += __expf(sb[t] - m);
    #pragma unroll
    for (int o = 32; o > 0; o >>= 1) z += __shfl_down(z, o, 64);
    if (lane == 0) red[wv] = z;
    __syncthreads();
    if (tid == 0) {
        z = red[0] + red[1] + red[2] + red[3];
        mz[b * 2]     = m;
        mz[b * 2 + 1] = 1.0f / z;
    }
}

// ---------------------------------------------------------------------------
// Kernel 3: pooling from bf16 xn. w_t = __expf(s_t - m) * inv computed inline
// (bit-identical to the old separate softmax write). Wave owns 16 tokens.
// ---------------------------------------------------------------------------
__global__ __launch_bounds__(256)
void k3_pool(const short* __restrict__ xnb, const float* __restrict__ s,
             const float* __restrict__ mz, float* __restrict__ partial)
{
    const int tid  = threadIdx.x;
    const int lane = tid & 63;
    const int wv   = tid >> 6;
    const int b    = blockIdx.x / NCH3, ch = blockIdx.x % NCH3;
    const int t0   = b * T_ + ch * CHT3 + wv * 16;

    const float m   = mz[b * 2];
    const float inv = mz[b * 2 + 1];

    float acc[12];
    #pragma unroll
    for (int k = 0; k < 12; ++k) acc[k] = 0.0f;

    for (int tt = 0; tt < 16; ++tt) {
        int t = t0 + tt;
        const short* row = xnb + (size_t)t * D_;
        float wt = __expf(s[t] - m) * inv;
        s16x8 v0 = *(const s16x8*)&row[8 * lane];
        s16x4 v1 = *(const s16x4*)&row[512 + 4 * lane];
        #pragma unroll
        for (int k = 0; k < 8; ++k) acc[k] = fmaf(wt, bf2f(v0[k]), acc[k]);
        #pragma unroll
        for (int k = 0; k < 4; ++k) acc[8 + k] = fmaf(wt, bf2f(v1[k]), acc[8 + k]);
    }

    float* p = partial + ((size_t)blockIdx.x * 4 + wv) * D_;
    *(f32x4*)&p[8 * lane]       = (f32x4){acc[0], acc[1], acc[2], acc[3]};
    *(f32x4*)&p[8 * lane + 4]   = (f32x4){acc[4], acc[5], acc[6], acc[7]};
    *(f32x4*)&p[512 + 4 * lane] = (f32x4){acc[8], acc[9], acc[10], acc[11]};
}

// ---------------------------------------------------------------------------
// Kernel 4: reduce 512 wave-partials per batch -> out[b, 768].
// ---------------------------------------------------------------------------
__global__ __launch_bounds__(256)
void k4_reduce(const float* __restrict__ partial, float* __restrict__ out)
{
    const int b = blockIdx.x, tid = threadIdx.x;
    const int NR = NCH3 * 4;
    #pragma unroll
    for (int k = 0; k < 3; ++k) {
        int j = tid + k * 256;
        const float* p = partial + (size_t)b * NR * D_ + j;
        float s = 0.0f;
        for (int c = 0; c < NR; ++c) s += p[(size_t)c * D_];
        out[b * D_ + j] = s;
    }
}

// ---------------------------------------------------------------------------
extern "C" void kernel_launch(void* const* d_in, const int* in_sizes, int n_in,
                              void* d_out, int out_size, void* d_ws, size_t ws_size,
                              hipStream_t stream)
{
    const float* x     = (const float*)d_in[0];
    // d_in[1] = lens (unused: uniform == L_IN, reference ignores it)
    const float* gamma = (const float*)d_in[2];
    const float* beta  = (const float*)d_in[3];
    const float* Wa    = (const float*)d_in[4];
    const float* ba    = (const float*)d_in[5];
    const float* Wb    = (const float*)d_in[6];
    const float* bb    = (const float*)d_in[7];
    const float* Wc    = (const float*)d_in[8];
    const float* bc    = (const float*)d_in[9];
    float* out = (float*)d_out;

    float* ws      = (float*)d_ws;
    float* s       = ws;                                   // B*T f32
    float* mz      = s + B_ * T_;                          // 16 f32
    float* partial = mz + 16;                              // B*NCH3*4*768 f32
    short* wtA     = (short*)(partial + (size_t)B_ * NCH3 * 4 * D_);
    short* wtB     = wtA + H_ * E_ * E_;
    short* xnb     = wtB + H_ * E_ * E_;                   // B*T*768 bf16 (96 MB)

    hipLaunchKernelGGL(k0_wprep, dim3((H_ * E_ * E_ + 255) / 256), dim3(256), 0, stream,
                       Wa, Wb, wtA, wtB);
    hipLaunchKernelGGL(kA_resln, dim3(NWA / 4), dim3(256), 0, stream,
                       x, gamma, beta, xnb);
    hipLaunchKernelGGL(kB_score, dim3(B_ * T_ / TT), dim3(256), 0, stream,
                       xnb, wtA, wtB, ba, bb, Wc, bc, s);
    hipLaunchKernelGGL(k2_mz, dim3(B_), dim3(256), 0, stream, s, mz);
    hipLaunchKernelGGL(k3_pool, dim3(B_ * NCH3), dim3(256), 0, stream,
                       xnb, s, mz, partial);
    hipLaunchKernelGGL(k4_reduce, dim3(B_), dim3(256), 0, stream, partial, out);
}

// Round 11
// 244.828 us; speedup vs baseline: 1.3086x; 1.2090x over previous
//
#include <hip/hip_runtime.h>
#include <math.h>

// Problem constants (fixed by setup_inputs)
#define B_    8
#define T_    8192
#define LIN   1536
#define D_    768
#define H_    8
#define E_    96
#define TT    16            // tokens per block in kB (24KB LDS -> 6 blocks/CU)
#define NWA   8192          // total waves in kA (2048 blocks x 4 waves); 8 tokens/wave
#define NCH3  64            // chunks per batch in k3
#define CHT3  (T_ / NCH3)   // 128 tokens per chunk (32 per wave)

typedef float f32x4 __attribute__((ext_vector_type(4)));
typedef short s16x8 __attribute__((ext_vector_type(8)));
typedef short s16x4 __attribute__((ext_vector_type(4)));

static __device__ __forceinline__ float fast_sigmoid(float v) {
    return 1.0f / (1.0f + __expf(-v));
}
static __device__ __forceinline__ float fast_tanh(float v) {
    float t = __expf(-2.0f * v);
    return (1.0f - t) / (1.0f + t);
}
static __device__ __forceinline__ short f2bf(float f) {   // RNE f32 -> bf16 bits
    unsigned u = __float_as_uint(f);
    unsigned r = (u + 0x7FFFu + ((u >> 16) & 1u)) >> 16;
    return (short)r;
}
static __device__ __forceinline__ float bf2f(short s) {
    return __uint_as_float(((unsigned)(unsigned short)s) << 16);
}

// ---------------------------------------------------------------------------
// Kernel 0: weight prep. Wa,Wb [h][e][f] f32 -> wtA,wtB [h][f][e] bf16.
// ---------------------------------------------------------------------------
__global__ __launch_bounds__(256)
void k0_wprep(const float* __restrict__ Wa, const float* __restrict__ Wb,
              short* __restrict__ wtA, short* __restrict__ wtB)
{
    int o = blockIdx.x * 256 + threadIdx.x;
    if (o >= H_ * E_ * E_) return;
    int e = o % E_;
    int f = (o / E_) % E_;
    int h = o / (E_ * E_);
    int in = h * E_ * E_ + e * E_ + f;
    wtA[o] = f2bf(Wa[in]);
    wtB[o] = f2bf(Wb[in]);
}

// ---------------------------------------------------------------------------
// Kernel A: resize + LayerNorm; wave owns 8 CONTIGUOUS tokens; explicit
// 1-ahead prefetch: token t+1's 6 dwordx4 issue before token t's shuffle
// reduce, keeping ~6KB/wave in flight during compute (fixes memory
// duty-cycle under-subscription). Math bit-identical to R10 (passed):
// same (c,d) accumulation order, same j=767 wl==0 clamp fixup.
// ---------------------------------------------------------------------------
__global__ __launch_bounds__(256)
void kA_resln(const float* __restrict__ x,
              const float* __restrict__ gamma, const float* __restrict__ beta,
              short* __restrict__ xnb)
{
    const int tid  = threadIdx.x;
    const int lane = tid & 63;
    const int wv   = tid >> 6;
    const int gw   = blockIdx.x * 4 + wv;   // 0..NWA-1

    const float SCALE = (float)(1535.0 / 767.0);
    float gm[12], btv[12], wl[12];
    #pragma unroll
    for (int c = 0; c < 3; ++c)
        #pragma unroll
        for (int d = 0; d < 4; ++d) {
            int k = 4 * c + d;
            int j = 256 * c + 4 * lane + d;
            float pos = (float)j * SCALE;
            int a = (int)floorf(pos);
            if (a > LIN - 1) a = LIN - 1;
            wl[k] = pos - (float)a;
            gm[k]  = gamma[j];
            btv[k] = beta[j];
        }
    const bool last = (lane == 63);

    const size_t tok0 = (size_t)gw * 8;
    const float* base = x + tok0 * LIN;

    // prefetch token 0
    f32x4 La0 = *(const f32x4*)&base[           8 * lane];
    f32x4 Lb0 = *(const f32x4*)&base[           8 * lane + 4];
    f32x4 La1 = *(const f32x4*)&base[512  +     8 * lane];
    f32x4 Lb1 = *(const f32x4*)&base[512  +     8 * lane + 4];
    f32x4 La2 = *(const f32x4*)&base[1024 +     8 * lane];
    f32x4 Lb2 = *(const f32x4*)&base[1024 +     8 * lane + 4];

    #pragma unroll
    for (int tt = 0; tt < 8; ++tt) {
        // issue next token's loads FIRST (in flight during this token's compute)
        f32x4 Na0, Nb0, Na1, Nb1, Na2, Nb2;
        if (tt < 7) {
            const float* nr = base + (size_t)(tt + 1) * LIN;
            Na0 = *(const f32x4*)&nr[           8 * lane];
            Nb0 = *(const f32x4*)&nr[           8 * lane + 4];
            Na1 = *(const f32x4*)&nr[512  +     8 * lane];
            Nb1 = *(const f32x4*)&nr[512  +     8 * lane + 4];
            Na2 = *(const f32x4*)&nr[1024 +     8 * lane];
            Nb2 = *(const f32x4*)&nr[1024 +     8 * lane + 4];
        }

        float xr[12];
        float sum = 0.0f, ssq = 0.0f;
        #pragma unroll
        for (int c = 0; c < 3; ++c) {
            f32x4 A = (c == 0) ? La0 : (c == 1) ? La1 : La2;
            f32x4 Bv = (c == 0) ? Lb0 : (c == 1) ? Lb1 : Lb2;
            #pragma unroll
            for (int d = 0; d < 4; ++d) {
                int k = 4 * c + d;
                int idx = (d & 1) * 2;
                float lo = (d < 2) ? A[idx]     : Bv[idx];
                float hi = (d < 2) ? A[idx + 1] : Bv[idx + 1];
                if (c == 2 && d == 3 && last && wl[k] == 0.0f)
                    lo = Lb2[3];               // j=767 clamp (pos rounds to 1535.0)
                float v = lo * (1.0f - wl[k]) + hi * wl[k];
                xr[k] = v; sum += v; ssq = fmaf(v, v, ssq);
            }
        }

        #pragma unroll
        for (int o = 1; o < 64; o <<= 1) {
            sum += __shfl_xor(sum, o, 64);
            ssq += __shfl_xor(ssq, o, 64);
        }
        float mu = sum * (1.0f / D_);
        float rs = 1.0f / sqrtf(ssq * (1.0f / D_) - mu * mu + 1e-5f);

        short* dst = xnb + (tok0 + tt) * D_;
        #pragma unroll
        for (int c = 0; c < 3; ++c) {
            s16x4 p;
            #pragma unroll
            for (int d = 0; d < 4; ++d) {
                int k = 4 * c + d;
                p[d] = f2bf((xr[k] - mu) * rs * gm[k] + btv[k]);
            }
            *(s16x4*)&dst[256 * c + 4 * lane] = p;
        }

        if (tt < 7) {
            La0 = Na0; Lb0 = Nb0; La1 = Na1; Lb1 = Nb1; La2 = Na2; Lb2 = Nb2;
        }
    }
}

// ---------------------------------------------------------------------------
// Kernel B: MFMA scoring, 16-token tile (24KB LDS). Byte-identical to R10
// (passed): coalesced s16x8 loads -> head-major XOR-swizzled LDS; wave owns
// 2 heads x 16 tokens.
// ---------------------------------------------------------------------------
__global__ __launch_bounds__(256)
void kB_score(const short* __restrict__ xnb,
              const short* __restrict__ wtA, const short* __restrict__ wtB,
              const float* __restrict__ ba, const float* __restrict__ bb,
              const float* __restrict__ Wc, const float* __restrict__ bc,
              float* __restrict__ s_out)
{
    __shared__ __align__(16) short xnt[TT * D_];   // 24 KB bf16 tile
    __shared__ float red2[TT][4];

    const int tid  = threadIdx.x;
    const int lane = tid & 63;
    const int wv   = tid >> 6;
    const int bt0  = blockIdx.x * TT;

    #pragma unroll
    for (int i = 0; i < 6; ++i) {
        int chunk = i * 256 + tid;
        int tok   = chunk / 96;
        int e     = chunk % 96;
        s16x8 v = *(const s16x8*)&xnb[(size_t)(bt0 + tok) * D_ + e * 8];
        int base = tok * D_;
        int swz  = (tok & 7) << 3;
        #pragma unroll
        for (int h = 0; h < 8; ++h) {
            int sidx = (base + h * E_ + e) ^ swz;
            xnt[sidx] = v[h];
        }
    }
    __syncthreads();

    const int ln15 = lane & 15;
    const int q    = lane >> 4;
    const int tokA = ln15;
    const int swzA = (tokA & 7) << 3;

    float hacc[4] = {0.0f, 0.0f, 0.0f, 0.0f};

    #pragma unroll
    for (int hh = 0; hh < 2; ++hh) {
        const int h = wv * 2 + hh;
        s16x8 afr[3];
        #pragma unroll
        for (int kk = 0; kk < 3; ++kk) {
            int sidx = (tokA * D_ + h * E_ + kk * 32 + q * 8) ^ swzA;
            afr[kk] = *(const s16x8*)&xnt[sidx];
        }
        f32x4 accA[6], accG[6];
        #pragma unroll
        for (int nt = 0; nt < 6; ++nt) {
            accA[nt] = (f32x4){0.f, 0.f, 0.f, 0.f};
            accG[nt] = (f32x4){0.f, 0.f, 0.f, 0.f};
        }
        #pragma unroll
        for (int nt = 0; nt < 6; ++nt) {
            const short* rowA = wtA + h * (E_ * E_) + (nt * 16 + ln15) * E_ + q * 8;
            const short* rowB = wtB + h * (E_ * E_) + (nt * 16 + ln15) * E_ + q * 8;
            #pragma unroll
            for (int kk = 0; kk < 3; ++kk) {
                s16x8 bA = *(const s16x8*)(rowA + kk * 32);
                s16x8 bG = *(const s16x8*)(rowB + kk * 32);
                accA[nt] = __builtin_amdgcn_mfma_f32_16x16x32_bf16(afr[kk], bA, accA[nt], 0, 0, 0);
                accG[nt] = __builtin_amdgcn_mfma_f32_16x16x32_bf16(afr[kk], bG, accG[nt], 0, 0, 0);
            }
        }
        float v0 = 0.f, v1 = 0.f, v2 = 0.f, v3 = 0.f;
        #pragma unroll
        for (int nt = 0; nt < 6; ++nt) {
            int f = nt * 16 + ln15;
            float bav = ba[h * E_ + f];
            float bbv = bb[h * E_ + f];
            float wcv = Wc[h * E_ + f];
            v0 += fast_tanh(accA[nt][0] + bav) * fast_sigmoid(accG[nt][0] + bbv) * wcv;
            v1 += fast_tanh(accA[nt][1] + bav) * fast_sigmoid(accG[nt][1] + bbv) * wcv;
            v2 += fast_tanh(accA[nt][2] + bav) * fast_sigmoid(accG[nt][2] + bbv) * wcv;
            v3 += fast_tanh(accA[nt][3] + bav) * fast_sigmoid(accG[nt][3] + bbv) * wcv;
        }
        hacc[0] += v0; hacc[1] += v1; hacc[2] += v2; hacc[3] += v3;
    }

    #pragma unroll
    for (int r = 0; r < 4; ++r) {
        float v = hacc[r];
        v += __shfl_xor(v, 1, 64);
        v += __shfl_xor(v, 2, 64);
        v += __shfl_xor(v, 4, 64);
        v += __shfl_xor(v, 8, 64);
        hacc[r] = v;
    }
    if (ln15 == 0) {
        #pragma unroll
        for (int r = 0; r < 4; ++r)
            red2[q * 4 + r][wv] = hacc[r];
    }
    __syncthreads();

    if (tid < TT) {
        float bcsum = 0.0f;
        #pragma unroll
        for (int h2 = 0; h2 < H_; ++h2) bcsum += bc[h2];
        s_out[bt0 + tid] = (red2[tid][0] + red2[tid][1] + red2[tid][2] + red2[tid][3]
                            + bcsum) * (1.0f / H_);
    }
}

// ---------------------------------------------------------------------------
// Kernel 2a: per-1024-token chunk max + sum(exp(s - m_c)). grid = B*8.
// Chunk data lives in registers (4 floats/thread): ONE global pass.
// ---------------------------------------------------------------------------
__global__ __launch_bounds__(256)
void k2a_chunk(const float* __restrict__ s, float* __restrict__ mzc)
{
    __shared__ float red[8];
    const int blk = blockIdx.x, tid = threadIdx.x, lane = tid & 63, wv = tid >> 6;
    const float* sb = s + (size_t)blk * 1024;

    float v0 = sb[tid], v1 = sb[tid + 256], v2 = sb[tid + 512], v3 = sb[tid + 768];

    float m = fmaxf(fmaxf(v0, v1), fmaxf(v2, v3));
    #pragma unroll
    for (int o = 32; o > 0; o >>= 1) m = fmaxf(m, __shfl_down(m, o, 64));
    if (lane == 0) red[wv] = m;
    __syncthreads();
    m = fmaxf(fmaxf(red[0], red[1]), fmaxf(red[2], red[3]));
    __syncthreads();

    float z = __expf(v0 - m) + __expf(v1 - m) + __expf(v2 - m) + __expf(v3 - m);
    #pragma unroll
    for (int o = 32; o > 0; o >>= 1) z += __shfl_down(z, o, 64);
    if (lane == 0) red[wv] = z;
    __syncthreads();
    if (tid == 0) {
        mzc[blk * 2]     = m;
        mzc[blk * 2 + 1] = red[0] + red[1] + red[2] + red[3];
    }
}

// ---------------------------------------------------------------------------
// Kernel 2b: combine 8 chunk (m,z) -> per-batch (m, 1/z). grid = B, 1 wave.
// ---------------------------------------------------------------------------
__global__ __launch_bounds__(64)
void k2b_comb(const float* __restrict__ mzc, float* __restrict__ mz)
{
    const int b = blockIdx.x, lane = threadIdx.x;
    float mloc = (lane < 8) ? mzc[(b * 8 + lane) * 2]     : -INFINITY;
    float zloc = (lane < 8) ? mzc[(b * 8 + lane) * 2 + 1] : 0.0f;
    float m = mloc;
    m = fmaxf(m, __shfl_xor(m, 1, 64));
    m = fmaxf(m, __shfl_xor(m, 2, 64));
    m = fmaxf(m, __shfl_xor(m, 4, 64));
    float z = zloc * __expf(mloc - m);     // exp(-inf)=0 for idle lanes
    z += __shfl_xor(z, 1, 64);
    z += __shfl_xor(z, 2, 64);
    z += __shfl_xor(z, 4, 64);
    if (lane == 0) { mz[b * 2] = m; mz[b * 2 + 1] = 1.0f / z; }
}

// ---------------------------------------------------------------------------
// Kernel 3: pooling from bf16 xn; w_t = exp(s_t-m)*inv inline. Wave owns 32
// tokens; block LDS-reduces its 4 wave-partials -> ONE partial row per block
// (64 per batch), making k4 8x cheaper.
// ---------------------------------------------------------------------------
__global__ __launch_bounds__(256)
void k3_pool(const short* __restrict__ xnb, const float* __restrict__ s,
             const float* __restrict__ mz, float* __restrict__ partial)
{
    __shared__ float red[4][D_];   // 12 KB
    const int tid  = threadIdx.x;
    const int lane = tid & 63;
    const int wv   = tid >> 6;
    const int b    = blockIdx.x / NCH3, ch = blockIdx.x % NCH3;
    const int t0   = b * T_ + ch * CHT3 + wv * 32;

    const float m   = mz[b * 2];
    const float inv = mz[b * 2 + 1];

    float acc[12];
    #pragma unroll
    for (int k = 0; k < 12; ++k) acc[k] = 0.0f;

    for (int tt = 0; tt < 32; ++tt) {
        int t = t0 + tt;
        const short* row = xnb + (size_t)t * D_;
        float wt = __expf(s[t] - m) * inv;
        s16x8 v0 = *(const s16x8*)&row[8 * lane];
        s16x4 v1 = *(const s16x4*)&row[512 + 4 * lane];
        #pragma unroll
        for (int k = 0; k < 8; ++k) acc[k] = fmaf(wt, bf2f(v0[k]), acc[k]);
        #pragma unroll
        for (int k = 0; k < 4; ++k) acc[8 + k] = fmaf(wt, bf2f(v1[k]), acc[8 + k]);
    }

    *(f32x4*)&red[wv][8 * lane]       = (f32x4){acc[0], acc[1], acc[2], acc[3]};
    *(f32x4*)&red[wv][8 * lane + 4]   = (f32x4){acc[4], acc[5], acc[6], acc[7]};
    *(f32x4*)&red[wv][512 + 4 * lane] = (f32x4){acc[8], acc[9], acc[10], acc[11]};
    __syncthreads();

    float* p = partial + (size_t)blockIdx.x * D_;
    #pragma unroll
    for (int k = 0; k < 3; ++k) {
        int j = tid + k * 256;
        p[j] = ((red[0][j] + red[1][j]) + red[2][j]) + red[3][j];
    }
}

// ---------------------------------------------------------------------------
// Kernel 4: reduce 64 chunk-partials per batch -> out[b, 768].
// ---------------------------------------------------------------------------
__global__ __launch_bounds__(256)
void k4_reduce(const float* __restrict__ partial, float* __restrict__ out)
{
    const int b = blockIdx.x, tid = threadIdx.x;
    #pragma unroll
    for (int k = 0; k < 3; ++k) {
        int j = tid + k * 256;
        const float* p = partial + (size_t)b * NCH3 * D_ + j;
        float sum = 0.0f;
        for (int c = 0; c < NCH3; ++c) sum += p[(size_t)c * D_];
        out[b * D_ + j] = sum;
    }
}

// ---------------------------------------------------------------------------
extern "C" void kernel_launch(void* const* d_in, const int* in_sizes, int n_in,
                              void* d_out, int out_size, void* d_ws, size_t ws_size,
                              hipStream_t stream)
{
    const float* x     = (const float*)d_in[0];
    // d_in[1] = lens (unused: uniform == L_IN, reference ignores it)
    const float* gamma = (const float*)d_in[2];
    const float* beta  = (const float*)d_in[3];
    const float* Wa    = (const float*)d_in[4];
    const float* ba    = (const float*)d_in[5];
    const float* Wb    = (const float*)d_in[6];
    const float* bb    = (const float*)d_in[7];
    const float* Wc    = (const float*)d_in[8];
    const float* bc    = (const float*)d_in[9];
    float* out = (float*)d_out;

    float* ws      = (float*)d_ws;
    float* s       = ws;                                   // B*T f32
    float* mzc     = s + B_ * T_;                          // 128 f32
    float* mz      = mzc + 128;                            // 16 f32
    float* partial = mz + 16;                              // B*64*768 f32 (1.6 MB)
    short* wtA     = (short*)(partial + (size_t)B_ * NCH3 * D_);
    short* wtB     = wtA + H_ * E_ * E_;
    short* xnb     = wtB + H_ * E_ * E_;                   // B*T*768 bf16 (96 MB)

    hipLaunchKernelGGL(k0_wprep, dim3((H_ * E_ * E_ + 255) / 256), dim3(256), 0, stream,
                       Wa, Wb, wtA, wtB);
    hipLaunchKernelGGL(kA_resln, dim3(NWA / 4), dim3(256), 0, stream,
                       x, gamma, beta, xnb);
    hipLaunchKernelGGL(kB_score, dim3(B_ * T_ / TT), dim3(256), 0, stream,
                       xnb, wtA, wtB, ba, bb, Wc, bc, s);
    hipLaunchKernelGGL(k2a_chunk, dim3(B_ * 8), dim3(256), 0, stream, s, mzc);
    hipLaunchKernelGGL(k2b_comb, dim3(B_), dim3(64), 0, stream, mzc, mz);
    hipLaunchKernelGGL(k3_pool, dim3(B_ * NCH3), dim3(256), 0, stream,
                       xnb, s, mz, partial);
    hipLaunchKernelGGL(k4_reduce, dim3(B_), dim3(256), 0, stream, partial, out);
}